// Round 6
// baseline (156.205 us; speedup 1.0000x reference)
//
#include <hip/hip_runtime.h>
#include <hip/hip_bf16.h>

#define B_DIM 4096
#define M_DIM 4096
#define K_DIM 4096
#define NCODE 512

typedef __attribute__((ext_vector_type(4))) float f32x4;
typedef __attribute__((ext_vector_type(16))) float f32x16;
typedef __attribute__((ext_vector_type(8))) short short8;

__device__ __forceinline__ unsigned short f2bf(float f) {
    union { float f; unsigned u; } c; c.f = f;
    unsigned u = c.u;
    return (unsigned short)((u + 0x7FFFu + ((u >> 16) & 1u)) >> 16);
}

// ---------------------------------------------------------------------------
// Fused prep: blocks [0,8192) dequantize codes -> bf16 W; [8192,16384) cvt A.
// ---------------------------------------------------------------------------
__global__ __launch_bounds__(256) void prep_kernel(const int* __restrict__ Q,
                                                   const float* __restrict__ cb,
                                                   short* __restrict__ Wout,
                                                   const float* __restrict__ in,
                                                   short* __restrict__ Ab) {
    const int b = blockIdx.x;
    if (b < 8192) {
        const int t = b * 256 + threadIdx.x;
        const int code = Q[t] & 0xFFFF;
        const float4* g = (const float4*)(cb + (size_t)code * 8);
        const float4 v0 = g[0];
        const float4 v1 = g[1];
        short8 o;
        o[0] = f2bf(v0.x); o[1] = f2bf(v0.y); o[2] = f2bf(v0.z); o[3] = f2bf(v0.w);
        o[4] = f2bf(v1.x); o[5] = f2bf(v1.y); o[6] = f2bf(v1.z); o[7] = f2bf(v1.w);
        *(short8*)(Wout + (size_t)t * 8) = o;
    } else {
        const int t = (b - 8192) * 256 + threadIdx.x;
        const float4* p = (const float4*)(in + (size_t)t * 8);
        const float4 v0 = p[0];
        const float4 v1 = p[1];
        short8 o;
        o[0] = f2bf(v0.x); o[1] = f2bf(v0.y); o[2] = f2bf(v0.z); o[3] = f2bf(v0.w);
        o[4] = f2bf(v1.x); o[5] = f2bf(v1.y); o[6] = f2bf(v1.z); o[7] = f2bf(v1.w);
        *(short8*)(Ab + (size_t)t * 8) = o;
    }
}

// ---------------------------------------------------------------------------
// GEMM: C[B,M] = A[B,K] * W[M,K]^T — 256x256 block tile, BK=32, 4 waves
// (2x2, each 128x128 via 4x4 subtiles of 32x32), mfma_f32_32x32x16_bf16,
// 1 wave/SIMD, 4-deep LDS ring, counted vmcnt(12), register phase pipeline.
// Frag layout (32x32x16): A row = lane&31, k = (lane>>5)*8 + e (8 contig bf16);
// B symmetric (col = lane&31). C/D: col = lane&31,
// row = (reg&3) + 8*(reg>>2) + 4*(lane>>5)  [m74/m101 verified].
// LDS unit-swizzle: stored unit = u ^ ((row>>1)&3) -> conflict-free b128 reads
// (2 lanes/16B-slot per 16-lane quarter); GLOBAL source inverse-swizzled.
// Hazard proof (same skeleton as verified r3-r5 kernel):
//  - visibility: vmcnt(12) at iter t leaves A(t+2),B(t+2),A(t+3)=12 in flight,
//    drains A(t+1),B(t+1); B1 makes tile t+1 workgroup-visible. All bufn reads
//    sit after B1.
//  - overwrite: GLD into buf((t+3)&3) issued at iter t pre-B1; last reads of
//    that buffer (a1@t-1 pre-B1, aN/bN@t-2) drained by lgkmcnt(0) before
//    B2(t-1) < GLD issue. Prologue: vmcnt(16)+barrier covers tile 0.
// ---------------------------------------------------------------------------
#define BM 256
#define BN 256
#define BK 32
#define NT (K_DIM / BK)   // 128

#define GLD(src, dst) \
    __builtin_amdgcn_global_load_lds( \
        (const __attribute__((address_space(1))) void*)(src), \
        (__attribute__((address_space(3))) void*)(dst), 16, 0, 0)

#define MFMA32(a, b, c) __builtin_amdgcn_mfma_f32_32x32x16_bf16(a, b, c, 0, 0, 0)

__global__ __launch_bounds__(256, 1) void gemm_bt_kernel(const short* __restrict__ A,
                                                         const short* __restrict__ Wd,
                                                         float* __restrict__ C) {
    __shared__ short lds[4 * 16384];   // 4 ring bufs x (A 16KB | B 16KB) = 128KB

    const int tid  = threadIdx.x;
    const int wave = tid >> 6;
    const int lane = tid & 63;

    // XCD-chunked swizzle: 256 blocks -> 8 XCDs, each a 4x8 block chunk
    const int bid = blockIdx.x;
    const int xcd = bid & 7;
    const int s   = bid >> 3;
    const int by  = (xcd >> 1) * 4 + (s >> 3);
    const int bx  = (xcd & 1) * 8 + (s & 7);

    const int rowBase = by * BM;
    const int colBase = bx * BN;

    const int wr = wave >> 1;                 // 0..1  (128-row half)
    const int wc = wave & 1;                  // 0..1  (128-col half)

    // ---- staging (inverse-swizzled source unit) ----
    // slot c (0..3): row = c*64 + (tid>>2), stored unit = tid&3
    const int rA0 = tid >> 2;
    const int uu  = (tid & 3) ^ ((rA0 >> 1) & 3);
    const size_t aIdx = (size_t)(rowBase + rA0) * K_DIM + uu * 8;
    const size_t bIdx = (size_t)(colBase + rA0) * K_DIM + uu * 8;

    // ---- fragment read offsets (shorts) ----
    const int l31 = lane & 31;
    const int l5  = lane >> 5;
    const int sx  = (l31 >> 1) & 3;
    const int uk0 = ((l5)     ^ sx) * 8;      // kk=0 : k 0..15
    const int uk1 = ((l5 + 2) ^ sx) * 8;      // kk=1 : k 16..31
    const int aOff = (wr * 128 + l31) * 32;          // + ms*1024 + uk
    const int bOff = 8192 + (wc * 128 + l31) * 32;   // + ns*1024 + uk

    f32x16 acc[4][4] = {};
    short8 aX[4], bX[8], aY[4], bY[8], a1[4];

    // ---- prologue: stage tiles 0,1,2 (24 GLDs/thread) ----
#pragma unroll
    for (int p = 0; p < 3; ++p) {
        const int koff = p * BK;
        short* base = &lds[p * 16384];
#pragma unroll
        for (int c = 0; c < 4; ++c)
            GLD(A + aIdx + koff + c * (64 * K_DIM), base + c * 2048 + wave * 512);
#pragma unroll
        for (int c = 0; c < 4; ++c)
            GLD(Wd + bIdx + koff + c * (64 * K_DIM), base + 8192 + c * 2048 + wave * 512);
    }
    asm volatile("s_waitcnt vmcnt(16)" ::: "memory");   // tile 0 landed
    __builtin_amdgcn_s_barrier();
#pragma unroll
    for (int i = 0; i < 4; ++i)
        aX[i] = *(const short8*)&lds[aOff + (i >> 1) * 1024 + ((i & 1) ? uk1 : uk0)];
#pragma unroll
    for (int j = 0; j < 8; ++j)
        bX[j] = *(const short8*)&lds[bOff + (j >> 1) * 1024 + ((j & 1) ? uk1 : uk0)];

#define ITER_BODY(T, AC, BC, AN, BN_)                                         \
    {                                                                         \
        const int buf    = ((T) & 3) * 16384;                                 \
        const int bufn   = (((T) + 1) & 3) * 16384;                           \
        const int tpre   = ((T) + 3 < NT) ? ((T) + 3) : (NT - 1);             \
        const int kpre   = tpre * BK;                                         \
        const int bufpre = (((T) + 3) & 3) * 16384;                           \
        /* pre-B1: a1 = cur tile ms=2,3 ; issue A-GLDs for tile T+3 */        \
        _Pragma("unroll")                                                     \
        for (int i = 0; i < 4; ++i)                                           \
            a1[i] = *(const short8*)&lds[buf + aOff + (2 + (i >> 1)) * 1024 + \
                                         ((i & 1) ? uk1 : uk0)];              \
        _Pragma("unroll")                                                     \
        for (int c = 0; c < 4; ++c)                                           \
            GLD(A + aIdx + kpre + c * (64 * K_DIM),                           \
                &lds[bufpre + c * 2048 + wave * 512]);                        \
        asm volatile("s_waitcnt vmcnt(12)" ::: "memory");                     \
        __builtin_amdgcn_s_barrier();                                         \
        /* R1: 6 next-tile B frags ; MFMA ph0 ; B-GLDs */                     \
        _Pragma("unroll")                                                     \
        for (int j = 0; j < 6; ++j)                                           \
            BN_[j] = *(const short8*)&lds[bufn + bOff + (j >> 1) * 1024 +     \
                                          ((j & 1) ? uk1 : uk0)];             \
        __builtin_amdgcn_s_setprio(1);                                        \
        _Pragma("unroll")                                                     \
        for (int ms = 0; ms < 2; ++ms)                                        \
            _Pragma("unroll")                                                 \
            for (int ns = 0; ns < 4; ++ns)                                    \
                _Pragma("unroll")                                             \
                for (int kk = 0; kk < 2; ++kk)                                \
                    acc[ms][ns] = MFMA32(AC[ms * 2 + kk], BC[ns * 2 + kk],    \
                                         acc[ms][ns]);                        \
        __builtin_amdgcn_s_setprio(0);                                        \
        _Pragma("unroll")                                                     \
        for (int c = 0; c < 4; ++c)                                           \
            GLD(Wd + bIdx + kpre + c * (64 * K_DIM),                          \
                &lds[bufpre + 8192 + c * 2048 + wave * 512]);                 \
        asm volatile("s_waitcnt lgkmcnt(0)" ::: "memory");                    \
        __builtin_amdgcn_s_barrier();                                         \
        /* R2: remaining next-tile frags ; MFMA ph1 */                        \
        _Pragma("unroll")                                                     \
        for (int j = 6; j < 8; ++j)                                           \
            BN_[j] = *(const short8*)&lds[bufn + bOff + (j >> 1) * 1024 +     \
                                          ((j & 1) ? uk1 : uk0)];             \
        _Pragma("unroll")                                                     \
        for (int i = 0; i < 4; ++i)                                           \
            AN[i] = *(const short8*)&lds[bufn + aOff + (i >> 1) * 1024 +      \
                                         ((i & 1) ? uk1 : uk0)];              \
        __builtin_amdgcn_s_setprio(1);                                        \
        _Pragma("unroll")                                                     \
        for (int ms = 0; ms < 2; ++ms)                                        \
            _Pragma("unroll")                                                 \
            for (int ns = 0; ns < 4; ++ns)                                    \
                _Pragma("unroll")                                             \
                for (int kk = 0; kk < 2; ++kk)                                \
                    acc[ms + 2][ns] = MFMA32(a1[ms * 2 + kk], BC[ns * 2 + kk],\
                                             acc[ms + 2][ns]);                \
        __builtin_amdgcn_s_setprio(0);                                        \
    }

    for (int t2 = 0; t2 < NT; t2 += 2) {
        ITER_BODY(t2,     aX, bX, aY, bY)
        ITER_BODY(t2 + 1, aY, bY, aX, bX)
    }
#undef ITER_BODY

    // ---- epilogue: C/D col = lane&31, row = (reg&3) + 8*(reg>>2) + 4*l5 ----
    const int r0 = rowBase + wr * 128 + 4 * l5;
    const int c0 = colBase + wc * 128 + l31;
#pragma unroll
    for (int ms = 0; ms < 4; ++ms)
#pragma unroll
        for (int ns = 0; ns < 4; ++ns) {
            float* cp = C + (size_t)(r0 + ms * 32) * M_DIM + (c0 + ns * 32);
#pragma unroll
            for (int reg = 0; reg < 16; ++reg) {
                const int rr = (reg & 3) + 8 * (reg >> 2);
                cp[(size_t)rr * M_DIM] = acc[ms][ns][reg];
            }
        }
}

// ---------------------------------------------------------------------------
extern "C" void kernel_launch(void* const* d_in, const int* in_sizes, int n_in,
                              void* d_out, int out_size, void* d_ws, size_t ws_size,
                              hipStream_t stream) {
    const float* inp  = (const float*)d_in[0];
    const int*   qidx = (const int*)d_in[1];
    const float* cb   = (const float*)d_in[2];
    float* out = (float*)d_out;

    short* Wb = (short*)d_ws;
    short* Ab = Wb + (size_t)M_DIM * K_DIM;

    prep_kernel<<<16384, 256, 0, stream>>>(qidx, cb, Wb, inp, Ab);

    gemm_bt_kernel<<<256, 256, 0, stream>>>(Ab, Wb, out);
}

// Round 7
// 147.699 us; speedup vs baseline: 1.0576x; 1.0576x over previous
//
#include <hip/hip_runtime.h>
#include <hip/hip_bf16.h>

#define B_DIM 4096
#define M_DIM 4096
#define K_DIM 4096
#define NCODE 512

typedef __attribute__((ext_vector_type(4))) float f32x4;
typedef __attribute__((ext_vector_type(8))) short short8;

__device__ __forceinline__ unsigned short f2bf(float f) {
    union { float f; unsigned u; } c; c.f = f;
    unsigned u = c.u;
    return (unsigned short)((u + 0x7FFFu + ((u >> 16) & 1u)) >> 16);
}

// ---------------------------------------------------------------------------
// Fused prep: blocks [0,8192) dequantize codes -> bf16 W; [8192,16384) cvt A.
// ---------------------------------------------------------------------------
__global__ __launch_bounds__(256) void prep_kernel(const int* __restrict__ Q,
                                                   const float* __restrict__ cb,
                                                   short* __restrict__ Wout,
                                                   const float* __restrict__ in,
                                                   short* __restrict__ Ab) {
    const int b = blockIdx.x;
    if (b < 8192) {
        const int t = b * 256 + threadIdx.x;
        const int code = Q[t] & 0xFFFF;
        const float4* g = (const float4*)(cb + (size_t)code * 8);
        const float4 v0 = g[0];
        const float4 v1 = g[1];
        short8 o;
        o[0] = f2bf(v0.x); o[1] = f2bf(v0.y); o[2] = f2bf(v0.z); o[3] = f2bf(v0.w);
        o[4] = f2bf(v1.x); o[5] = f2bf(v1.y); o[6] = f2bf(v1.z); o[7] = f2bf(v1.w);
        *(short8*)(Wout + (size_t)t * 8) = o;
    } else {
        const int t = (b - 8192) * 256 + threadIdx.x;
        const float4* p = (const float4*)(in + (size_t)t * 8);
        const float4 v0 = p[0];
        const float4 v1 = p[1];
        short8 o;
        o[0] = f2bf(v0.x); o[1] = f2bf(v0.y); o[2] = f2bf(v0.z); o[3] = f2bf(v0.w);
        o[4] = f2bf(v1.x); o[5] = f2bf(v1.y); o[6] = f2bf(v1.z); o[7] = f2bf(v1.w);
        *(short8*)(Ab + (size_t)t * 8) = o;
    }
}

// ---------------------------------------------------------------------------
// GEMM: C[B,M] = A[B,K] * W[M,K]^T — 256x256 tile, BK=32, 8 waves (2x4, wave
// tile 128x64), mfma_f32_16x16x32_bf16, 4-deep LDS ring, counted vmcnt(6),
// m201-style SAME-PHASE read->wait->MFMA discipline:
//   phase A: {read a0-3,b0-3 (8 ds) || 2 GLD-A(t+3); vmcnt(6); bar;
//             lgkm(0); schedbar; prio1; 16 MFMA acc[0..3][*]; prio0; bar}
//   phase B: {read a4-7 (4 ds)     || 2 GLD-B(t+3); bar;
//             lgkm(0); schedbar; prio1; 16 MFMA acc[4..7][*]; prio0; bar}
// Hazard proof:
//  - visibility: vmcnt(6) at iter t drains all waves' GLDs through tile t+1
//    (in flight: t+1:4, t+2:4, t+3A:2 = 10 -> 6); barrier publishes. Tile t's
//    reads at iter t were covered by iter t-1's vmcnt(6). Prologue covers t0
//    via vmcnt(8)+barrier.
//  - overwrite: GLD(t+4 -> buf t&3) issues at iter t+1 phase A, after
//    barrier2(t,phB). All iter-t reads of buf(t&3) are drained by that wave's
//    own lgkm(0), which precedes a barrier the writer has since crossed.
// LDS unit-swizzle (conflict-free 16-row groups): stored unit = u^((row>>1)&3)
// with inverse-swizzled GLOBAL source (both-sides rule).
// ---------------------------------------------------------------------------
#define BM 256
#define BN 256
#define BK 32
#define NT (K_DIM / BK)   // 128

#define GLD(src, dst) \
    __builtin_amdgcn_global_load_lds( \
        (const __attribute__((address_space(1))) void*)(src), \
        (__attribute__((address_space(3))) void*)(dst), 16, 0, 0)

#define MFMA(a, b, c) __builtin_amdgcn_mfma_f32_16x16x32_bf16(a, b, c, 0, 0, 0)

__global__ __launch_bounds__(512, 2) void gemm_bt_kernel(const short* __restrict__ A,
                                                         const short* __restrict__ Wd,
                                                         float* __restrict__ C) {
    __shared__ short lds[4 * 16384];   // 4 ring bufs x (A 16KB | B 16KB)

    const int tid  = threadIdx.x;
    const int wave = tid >> 6;
    const int lane = tid & 63;

    // XCD-chunked swizzle: 256 blocks -> 8 XCDs, each a 4x8 block chunk
    const int bid = blockIdx.x;
    const int xcd = bid & 7;
    const int s   = bid >> 3;
    const int by  = (xcd >> 1) * 4 + (s >> 3);
    const int bx  = (xcd & 1) * 8 + (s & 7);

    const int rowBase = by * BM;
    const int colBase = bx * BN;

    const int wr = wave >> 2;                 // 0..1  (128-row half)
    const int wc = wave & 3;                  // 0..3  (64-col quarter)

    // stage sources (inverse-swizzled unit)
    const int rA0 = tid >> 2;
    const int uu  = (tid & 3) ^ ((rA0 >> 1) & 3);
    const short* aSrc0 = A  + (size_t)(rowBase + rA0) * K_DIM + uu * 8;
    const short* aSrc1 = A  + (size_t)(rowBase + rA0 + 128) * K_DIM + uu * 8;
    const short* bSrc0 = Wd + (size_t)(colBase + rA0) * K_DIM + uu * 8;
    const short* bSrc1 = Wd + (size_t)(colBase + rA0 + 128) * K_DIM + uu * 8;

    // ds_read per-lane base offsets (shorts); frag f adds f*512
    const int l15 = lane & 15;
    const int l4  = lane >> 4;
    const int sx  = (l15 >> 1) & 3;
    const int aRd = (wr * 128 + l15) * 32 + (l4 ^ sx) * 8;
    const int bRd = 8192 + (wc * 64 + l15) * 32 + (l4 ^ sx) * 8;

    f32x4 acc[8][4] = {};

    // prologue: stage tiles 0,1,2 (12 gloads/thread in flight)
#pragma unroll
    for (int p = 0; p < 3; ++p) {
        const int koff = p * BK;
        short* base = &lds[p * 16384];
        GLD(aSrc0 + koff, base + wave * 512);
        GLD(aSrc1 + koff, base + 4096 + wave * 512);
        GLD(bSrc0 + koff, base + 8192 + wave * 512);
        GLD(bSrc1 + koff, base + 12288 + wave * 512);
    }
    asm volatile("s_waitcnt vmcnt(8)" ::: "memory");   // tile 0 landed
    __builtin_amdgcn_s_barrier();

    for (int t = 0; t < NT; ++t) {
        const int buf    = (t & 3) * 16384;
        const int tpre   = (t + 3 < NT) ? (t + 3) : (NT - 1);
        const int kpre   = tpre * BK;
        const int bufpre = ((t + 3) & 3) * 16384;

        // ---------------- Phase A ----------------
        short8 a0[4], b0[4];
#pragma unroll
        for (int m = 0; m < 4; ++m)
            a0[m] = *(const short8*)&lds[buf + aRd + m * 512];
#pragma unroll
        for (int n = 0; n < 4; ++n)
            b0[n] = *(const short8*)&lds[buf + bRd + n * 512];
        GLD(aSrc0 + kpre, &lds[bufpre + wave * 512]);
        GLD(aSrc1 + kpre, &lds[bufpre + 4096 + wave * 512]);
        asm volatile("s_waitcnt vmcnt(6)" ::: "memory");  // tile t+1 landed
        __builtin_amdgcn_s_barrier();
        asm volatile("s_waitcnt lgkmcnt(0)" ::: "memory");
        __builtin_amdgcn_sched_barrier(0);
        __builtin_amdgcn_s_setprio(1);
#pragma unroll
        for (int m = 0; m < 4; ++m)
#pragma unroll
            for (int n = 0; n < 4; ++n)
                acc[m][n] = MFMA(a0[m], b0[n], acc[m][n]);
        __builtin_amdgcn_s_setprio(0);
        __builtin_amdgcn_s_barrier();

        // ---------------- Phase B ----------------
        short8 a1[4];
#pragma unroll
        for (int m = 0; m < 4; ++m)
            a1[m] = *(const short8*)&lds[buf + aRd + (m + 4) * 512];
        GLD(bSrc0 + kpre, &lds[bufpre + 8192 + wave * 512]);
        GLD(bSrc1 + kpre, &lds[bufpre + 12288 + wave * 512]);
        __builtin_amdgcn_s_barrier();
        asm volatile("s_waitcnt lgkmcnt(0)" ::: "memory");
        __builtin_amdgcn_sched_barrier(0);
        __builtin_amdgcn_s_setprio(1);
#pragma unroll
        for (int m = 0; m < 4; ++m)
#pragma unroll
            for (int n = 0; n < 4; ++n)
                acc[m + 4][n] = MFMA(a1[m], b0[n], acc[m + 4][n]);
        __builtin_amdgcn_s_setprio(0);
        __builtin_amdgcn_s_barrier();
    }

    // epilogue: C/D layout col = lane&15, row = (lane>>4)*4 + reg
    const int r0 = rowBase + wr * 128 + l4 * 4;
    const int c0 = colBase + wc * 64 + l15;
#pragma unroll
    for (int m = 0; m < 8; ++m)
#pragma unroll
        for (int n = 0; n < 4; ++n) {
            float* cp = C + (size_t)(r0 + m * 16) * M_DIM + (c0 + n * 16);
#pragma unroll
            for (int reg = 0; reg < 4; ++reg)
                cp[(size_t)reg * M_DIM] = acc[m][n][reg];
        }
}

// ---------------------------------------------------------------------------
extern "C" void kernel_launch(void* const* d_in, const int* in_sizes, int n_in,
                              void* d_out, int out_size, void* d_ws, size_t ws_size,
                              hipStream_t stream) {
    const float* inp  = (const float*)d_in[0];
    const int*   qidx = (const int*)d_in[1];
    const float* cb   = (const float*)d_in[2];
    float* out = (float*)d_out;

    short* Wb = (short*)d_ws;
    short* Ab = Wb + (size_t)M_DIM * K_DIM;

    prep_kernel<<<16384, 256, 0, stream>>>(qidx, cb, Wb, inp, Ab);

    gemm_bt_kernel<<<256, 512, 0, stream>>>(Ab, Wb, out);
}

// Round 8
// 133.277 us; speedup vs baseline: 1.1720x; 1.1082x over previous
//
#include <hip/hip_runtime.h>
#include <hip/hip_bf16.h>

#define B_DIM 4096
#define M_DIM 4096
#define K_DIM 4096
#define NCODE 512

typedef __attribute__((ext_vector_type(4))) float f32x4;
typedef __attribute__((ext_vector_type(8))) short short8;

__device__ __forceinline__ unsigned short f2bf(float f) {
    union { float f; unsigned u; } c; c.f = f;
    unsigned u = c.u;
    return (unsigned short)((u + 0x7FFFu + ((u >> 16) & 1u)) >> 16);
}

// ---------------------------------------------------------------------------
// Fused prep: blocks [0,8192) dequantize codes -> bf16 W; [8192,16384) cvt A.
// ---------------------------------------------------------------------------
__global__ __launch_bounds__(256) void prep_kernel(const int* __restrict__ Q,
                                                   const float* __restrict__ cb,
                                                   short* __restrict__ Wout,
                                                   const float* __restrict__ in,
                                                   short* __restrict__ Ab) {
    const int b = blockIdx.x;
    if (b < 8192) {
        const int t = b * 256 + threadIdx.x;
        const int code = Q[t] & 0xFFFF;
        const float4* g = (const float4*)(cb + (size_t)code * 8);
        const float4 v0 = g[0];
        const float4 v1 = g[1];
        short8 o;
        o[0] = f2bf(v0.x); o[1] = f2bf(v0.y); o[2] = f2bf(v0.z); o[3] = f2bf(v0.w);
        o[4] = f2bf(v1.x); o[5] = f2bf(v1.y); o[6] = f2bf(v1.z); o[7] = f2bf(v1.w);
        *(short8*)(Wout + (size_t)t * 8) = o;
    } else {
        const int t = (b - 8192) * 256 + threadIdx.x;
        const float4* p = (const float4*)(in + (size_t)t * 8);
        const float4 v0 = p[0];
        const float4 v1 = p[1];
        short8 o;
        o[0] = f2bf(v0.x); o[1] = f2bf(v0.y); o[2] = f2bf(v0.z); o[3] = f2bf(v0.w);
        o[4] = f2bf(v1.x); o[5] = f2bf(v1.y); o[6] = f2bf(v1.z); o[7] = f2bf(v1.w);
        *(short8*)(Ab + (size_t)t * 8) = o;
    }
}

// ---------------------------------------------------------------------------
// GEMM: C[B,M] = A[B,K] * W[M,K]^T — 256x256 tile, BK=64, 8 waves (2x4, wave
// tile 128x64), 16x16x32 MFMA, 2-deep LDS ring (128 KB), 4-phase register
// pipeline (phase p reads phase p+1's frags), 2 barriers per 64-k iter.
//   ph0: MFMA m0-3/h0 (frags from prev ph3/prologue) || read aH0[4-7] || 4 A-GLD(t+1)
//   ph1: MFMA m4-7/h0 || read aH1[0-3], bH1[0-3] || 4 B-GLD(t+1)
//   ph2: MFMA m0-3/h1 || read aH1[4-7] ; vmcnt(0) ; barrier  (t+1 published)
//   ph3: MFMA m4-7/h1 || read next-tile aH0[0-3],bH0[0-3] (other buffer)
//        lgkmcnt(8) ; barrier  (all buf(t) reads drained -> t+2 GLDs may target it)
// Hazard proof:
//  - visibility: each wave's 8 GLDs for t+1 issue in ph0/ph1; its vmcnt(0) at
//    ph2-end drains them; barrier joins all waves. ph3's bufn reads follow.
//  - overwrite: GLD(t+2)->buf(t&1) issues at iter t+1 ph0, after iter t's
//    final barrier; all buf(t) reads were consumed by iter-t MFMAs (compiler
//    waits) and fenced by lgkmcnt(8) (ph3's 8 bufn reads are the newest 8).
//  - prologue: stage tile 0, vmcnt(0)+barrier, read ph0 frags.
// LDS swizzle (BK=64 rows = 8 x 16B units): stored unit = u ^ (row&7);
// read-side XOR folds to per-lane constant; GLOBAL source inverse-swizzled
// (both-sides rule). 64 lanes spread uniformly over 8 bank-quads.
// ---------------------------------------------------------------------------
#define BM 256
#define BN 256
#define BK 64
#define NT (K_DIM / BK)   // 64

#define GLD(src, dst) \
    __builtin_amdgcn_global_load_lds( \
        (const __attribute__((address_space(1))) void*)(src), \
        (__attribute__((address_space(3))) void*)(dst), 16, 0, 0)

#define MFMA(a, b, c) __builtin_amdgcn_mfma_f32_16x16x32_bf16(a, b, c, 0, 0, 0)

__global__ __launch_bounds__(512, 2) void gemm_bt_kernel(const short* __restrict__ A,
                                                         const short* __restrict__ Wd,
                                                         float* __restrict__ C) {
    __shared__ short lds[2 * 32768];   // 2 bufs x (A 32KB | B 32KB) = 128 KB

    const int tid  = threadIdx.x;
    const int wave = tid >> 6;
    const int lane = tid & 63;

    // XCD-chunked swizzle: 256 blocks -> 8 XCDs, each a 4x8 block chunk
    const int bid = blockIdx.x;
    const int xcd = bid & 7;
    const int s   = bid >> 3;
    const int by  = (xcd >> 1) * 4 + (s >> 3);
    const int bx  = (xcd & 1) * 8 + (s & 7);

    const int rowBase = by * BM;
    const int colBase = bx * BN;

    const int wr = wave >> 2;                 // 0..1  (128-row half)
    const int wc = wave & 3;                  // 0..3  (64-col quarter)

    // ---- staging: thread covers rows (tid>>3)+c*64, stored unit tid&7 ----
    const int rA0 = tid >> 3;                 // 0..63
    const int uu  = (tid & 7) ^ (rA0 & 7);    // inverse-swizzled logical unit
    const int stOff = rA0 * 64 + (tid & 7) * 8;   // shorts; +c*4096; linear per wave
    const short* aSrcB = A  + (size_t)(rowBase + rA0) * K_DIM + uu * 8;
    const short* bSrcB = Wd + (size_t)(colBase + rA0) * K_DIM + uu * 8;

    // ---- fragment read offsets (shorts) ----
    const int l15 = lane & 15;
    const int l4  = lane >> 4;
    const int uk0 = ((l4 ^ (l15 & 7))) * 8;   // h=0 stored-unit offset
    const int uk1 = uk0 ^ 32;                 // h=1 (unit XOR 4)
    const int aRow = (wr * 128 + l15) * 64;           // + m*1024 + ukh
    const int bRow = 16384 + (wc * 64 + l15) * 64;    // + n*1024 + ukh

    f32x4 acc[8][4] = {};
    short8 aC[4], bC[4];      // ph0 operands (loop-carried, written at ph3)

    // ---- prologue: stage tile 0 into buf0, publish, read ph0 frags ----
#pragma unroll
    for (int c = 0; c < 4; ++c)
        GLD(aSrcB + c * (64 * K_DIM), &lds[c * 4096 + stOff]);
#pragma unroll
    for (int c = 0; c < 4; ++c)
        GLD(bSrcB + c * (64 * K_DIM), &lds[16384 + c * 4096 + stOff]);
    asm volatile("s_waitcnt vmcnt(0)" ::: "memory");
    __builtin_amdgcn_s_barrier();
#pragma unroll
    for (int m = 0; m < 4; ++m) aC[m] = *(const short8*)&lds[aRow + m * 1024 + uk0];
#pragma unroll
    for (int n = 0; n < 4; ++n) bC[n] = *(const short8*)&lds[bRow + n * 1024 + uk0];

    for (int t = 0; t < NT; ++t) {
        const int buf  = (t & 1) * 32768;
        const int bufn = buf ^ 32768;
        const size_t kpre = (size_t)(((t + 1 < NT) ? (t + 1) : (NT - 1)) * BK);

        // ---- ph0: MFMA m0-3 x h0 ; read aH0[4-7] ; issue 4 A-GLD(t+1) ----
        short8 a1h0[4];
#pragma unroll
        for (int m = 0; m < 4; ++m)
            a1h0[m] = *(const short8*)&lds[buf + aRow + (m + 4) * 1024 + uk0];
#pragma unroll
        for (int c = 0; c < 4; ++c)
            GLD(aSrcB + kpre + c * (64 * K_DIM), &lds[bufn + c * 4096 + stOff]);
        __builtin_amdgcn_s_setprio(1);
#pragma unroll
        for (int m = 0; m < 4; ++m)
#pragma unroll
            for (int n = 0; n < 4; ++n)
                acc[m][n] = MFMA(aC[m], bC[n], acc[m][n]);
        __builtin_amdgcn_s_setprio(0);

        // ---- ph1: MFMA m4-7 x h0 ; read aH1[0-3], bH1[0-3] ; 4 B-GLD ----
        short8 a0h1[4], b1[4];
#pragma unroll
        for (int m = 0; m < 4; ++m)
            a0h1[m] = *(const short8*)&lds[buf + aRow + m * 1024 + uk1];
#pragma unroll
        for (int n = 0; n < 4; ++n)
            b1[n] = *(const short8*)&lds[buf + bRow + n * 1024 + uk1];
#pragma unroll
        for (int c = 0; c < 4; ++c)
            GLD(bSrcB + kpre + c * (64 * K_DIM), &lds[bufn + 16384 + c * 4096 + stOff]);
        __builtin_amdgcn_s_setprio(1);
#pragma unroll
        for (int m = 0; m < 4; ++m)
#pragma unroll
            for (int n = 0; n < 4; ++n)
                acc[m + 4][n] = MFMA(a1h0[m], bC[n], acc[m + 4][n]);
        __builtin_amdgcn_s_setprio(0);

        // ---- ph2: MFMA m0-3 x h1 ; read aH1[4-7] ; vmcnt(0)+barrier ----
        short8 a1h1[4];
#pragma unroll
        for (int m = 0; m < 4; ++m)
            a1h1[m] = *(const short8*)&lds[buf + aRow + (m + 4) * 1024 + uk1];
        __builtin_amdgcn_s_setprio(1);
#pragma unroll
        for (int m = 0; m < 4; ++m)
#pragma unroll
            for (int n = 0; n < 4; ++n)
                acc[m][n] = MFMA(a0h1[m], b1[n], acc[m][n]);
        __builtin_amdgcn_s_setprio(0);
        asm volatile("s_waitcnt vmcnt(0)" ::: "memory");   // tile t+1 landed
        __builtin_amdgcn_s_barrier();

        // ---- ph3: MFMA m4-7 x h1 ; read next-tile ph0 frags from bufn ----
#pragma unroll
        for (int m = 0; m < 4; ++m)
            aC[m] = *(const short8*)&lds[bufn + aRow + m * 1024 + uk0];
#pragma unroll
        for (int n = 0; n < 4; ++n)
            bC[n] = *(const short8*)&lds[bufn + bRow + n * 1024 + uk0];
        __builtin_amdgcn_s_setprio(1);
#pragma unroll
        for (int m = 0; m < 4; ++m)
#pragma unroll
            for (int n = 0; n < 4; ++n)
                acc[m + 4][n] = MFMA(a1h1[m], b1[n], acc[m + 4][n]);
        __builtin_amdgcn_s_setprio(0);
        asm volatile("s_waitcnt lgkmcnt(8)" ::: "memory"); // buf(t) reads drained
        __builtin_amdgcn_s_barrier();
    }

    // epilogue: C/D layout col = lane&15, row = (lane>>4)*4 + reg
    const int r0 = rowBase + wr * 128 + l4 * 4;
    const int c0 = colBase + wc * 64 + l15;
#pragma unroll
    for (int m = 0; m < 8; ++m)
#pragma unroll
        for (int n = 0; n < 4; ++n) {
            float* cp = C + (size_t)(r0 + m * 16) * M_DIM + (c0 + n * 16);
#pragma unroll
            for (int reg = 0; reg < 4; ++reg)
                cp[(size_t)reg * M_DIM] = acc[m][n][reg];
        }
}

// ---------------------------------------------------------------------------
extern "C" void kernel_launch(void* const* d_in, const int* in_sizes, int n_in,
                              void* d_out, int out_size, void* d_ws, size_t ws_size,
                              hipStream_t stream) {
    const float* inp  = (const float*)d_in[0];
    const int*   qidx = (const int*)d_in[1];
    const float* cb   = (const float*)d_in[2];
    float* out = (float*)d_out;

    short* Wb = (short*)d_ws;
    short* Ab = Wb + (size_t)M_DIM * K_DIM;

    prep_kernel<<<16384, 256, 0, stream>>>(qidx, cb, Wb, inp, Ab);

    gemm_bt_kernel<<<256, 512, 0, stream>>>(Ab, Wb, out);
}